// Round 4
// baseline (1638.832 us; speedup 1.0000x reference)
//
#include <hip/hip_runtime.h>

#ifndef __has_builtin
#define __has_builtin(x) 0
#endif

typedef float v2 __attribute__((ext_vector_type(2)));

// ---- fast HW transcendentals (v_exp_f32 computes 2^x; v_rcp_f32) ----
__device__ __forceinline__ float fast_exp2(float x) {
#if __has_builtin(__builtin_amdgcn_exp2f)
  return __builtin_amdgcn_exp2f(x);
#else
  return exp2f(x);
#endif
}
__device__ __forceinline__ float fast_rcp(float x) {
#if __has_builtin(__builtin_amdgcn_rcpf)
  return __builtin_amdgcn_rcpf(x);
#else
  return 1.0f / x;
#endif
}

namespace {
constexpr int kB = 131072;
constexpr int kSeq = 150;
constexpr int kD = 2;
constexpr int kH = 64;
constexpr int kPred = 150;
constexpr int kSteps = kPred - 1;            // 149
constexpr float kDt = 150.0f / 149.0f;       // linspace(0,150,150) spacing
constexpr float kC = 2.8853900817779268f;    // 2*log2(e)
constexpr float kClamp = 30.0f;              // exp2 arg clamp (sigma err <1e-9)
constexpr int kSplit = 8;                    // lanes per batch element
constexpr int kHper = kH / kSplit;           // 8 hidden units per lane
constexpr int kBlock = 256;
constexpr int kElemsPerBlock = kBlock / kSplit;  // 32
}  // namespace

// Butterfly add across the 8 lanes of an element, all in-register DPP:
//  stage 1: quad_perm xor1 (0xB1), stage 2: quad_perm xor2 (0x4E),
//  stage 3: row_half_mirror (0x141) — after stages 1-2 every lane of a
//  4-group holds the identical 4-sum, so the half-row mirror pairs each
//  lane with *some* lane of the other 4-group, which is sufficient.
//  fp add is commutative -> all 8 lanes end bitwise identical.
template <int PAT>
__device__ __forceinline__ float dpp_add(float v) {
  int s = __builtin_amdgcn_update_dpp(0, __float_as_int(v), PAT, 0xF, 0xF, true);
  return v + __int_as_float(s);
}

// f(y) = tanh(y@W1+b1)@W2 + b2, folded:
//   tanh(q) = 1 - 2*rcp(1 + exp2(q*2log2e))
//   per-lane: 8 of 64 hidden units, in 2 groups of 4 with a SHARED
//   reciprocal: r_i = (prod_{j!=i} s_j) * rcp(prod s_j), s = 1+exp2(p).
// 40 weight floats/lane -> fits comfortably in VGPRs (the 16-unit split of
// rounds 1-3 needed 80 and the compiler spilled or re-streamed them).
__global__ __launch_bounds__(kBlock, 4) void ode_kernel(
    const float* __restrict__ x, const float* __restrict__ W1,
    const float* __restrict__ b1, const float* __restrict__ W2,
    const float* __restrict__ b2, float* __restrict__ out) {
  const int t = threadIdx.x;
  const int part = t & (kSplit - 1);
  const int j0 = part * kHper;

  // ---- weights, register-resident (all indices compile-time) ----
  float wx[kHper], wy[kHper], wb[kHper], wz[kHper], ww[kHper];
#pragma unroll
  for (int i = 0; i < kHper; ++i) {
    const int j = j0 + i;
    // W1 is (D,H) row-major; W2 is (H,D) row-major.
    wx[i] = W1[j] * kC;
    wy[i] = W1[kH + j] * kC;
    wb[i] = b1[j] * kC;
    wz[i] = -2.0f * W2[2 * j];
    ww[i] = -2.0f * W2[2 * j + 1];
  }
  // lane partial base: b2[d]/8 + sum_own_j W2[j][d]  (wz = -2*W2)
  float pb0 = 0.125f * b2[0];
  float pb1 = 0.125f * b2[1];
#pragma unroll
  for (int i = 0; i < kHper; ++i) {
    pb0 = fmaf(-0.5f, wz[i], pb0);
    pb1 = fmaf(-0.5f, ww[i], pb1);
  }
  // Light opacity barrier: keeps the *scaled* weights as the live values
  // (blocks kC-refolding + remat of raw loads). At 40 floats there is no
  // register pressure, so this cannot induce spills like round 3's 80.
#pragma unroll
  for (int i = 0; i < kHper; ++i) {
    asm volatile("" : "+v"(wx[i]), "+v"(wy[i]), "+v"(wb[i]), "+v"(wz[i]),
                      "+v"(ww[i]));
  }

  const long elem = (long)blockIdx.x * kElemsPerBlock + (t >> 3);
  const float* xp = x + elem * (long)(kSeq * kD) + (kSeq - 1) * kD;
  v2 y = *reinterpret_cast<const v2*>(xp);  // 8B aligned (offset 298*4)
  float* op = out + elem * (long)(kPred * kD);

  auto feval = [&](float u0, float u1, float& f0, float& f1) {
    // group A: units 0-3, group B: units 4-7 (independent chains -> ILP)
    float pA0 = fminf(fmaf(u0, wx[0], fmaf(u1, wy[0], wb[0])), kClamp);
    float pA1 = fminf(fmaf(u0, wx[1], fmaf(u1, wy[1], wb[1])), kClamp);
    float pA2 = fminf(fmaf(u0, wx[2], fmaf(u1, wy[2], wb[2])), kClamp);
    float pA3 = fminf(fmaf(u0, wx[3], fmaf(u1, wy[3], wb[3])), kClamp);
    float pB0 = fminf(fmaf(u0, wx[4], fmaf(u1, wy[4], wb[4])), kClamp);
    float pB1 = fminf(fmaf(u0, wx[5], fmaf(u1, wy[5], wb[5])), kClamp);
    float pB2 = fminf(fmaf(u0, wx[6], fmaf(u1, wy[6], wb[6])), kClamp);
    float pB3 = fminf(fmaf(u0, wx[7], fmaf(u1, wy[7], wb[7])), kClamp);
    float sA0 = 1.0f + fast_exp2(pA0);
    float sA1 = 1.0f + fast_exp2(pA1);
    float sA2 = 1.0f + fast_exp2(pA2);
    float sA3 = 1.0f + fast_exp2(pA3);
    float sB0 = 1.0f + fast_exp2(pB0);
    float sB1 = 1.0f + fast_exp2(pB1);
    float sB2 = 1.0f + fast_exp2(pB2);
    float sB3 = 1.0f + fast_exp2(pB3);
    // shared reciprocal per group of 4 (validated numerics, rounds 2-3)
    float mA01 = sA0 * sA1, mA23 = sA2 * sA3;
    float mB01 = sB0 * sB1, mB23 = sB2 * sB3;
    float RA = fast_rcp(mA01 * mA23);
    float RB = fast_rcp(mB01 * mB23);
    float tA01 = mA23 * RA, tA23 = mA01 * RA;
    float tB01 = mB23 * RB, tB23 = mB01 * RB;
    float rA0 = sA1 * tA01, rA1 = sA0 * tA01;
    float rA2 = sA3 * tA23, rA3 = sA2 * tA23;
    float rB0 = sB1 * tB01, rB1 = sB0 * tB01;
    float rB2 = sB3 * tB23, rB3 = sB2 * tB23;
    // accumulate: f_d = pb_d + sum_j r_j * w2_j_d   (two chains per dim)
    float a0 = fmaf(rA0, wz[0], pb0);
    float a1 = fmaf(rA0, ww[0], pb1);
    float c0 = rB0 * wz[4];
    float c1 = rB0 * ww[4];
    a0 = fmaf(rA1, wz[1], a0);
    a1 = fmaf(rA1, ww[1], a1);
    c0 = fmaf(rB1, wz[5], c0);
    c1 = fmaf(rB1, ww[5], c1);
    a0 = fmaf(rA2, wz[2], a0);
    a1 = fmaf(rA2, ww[2], a1);
    c0 = fmaf(rB2, wz[6], c0);
    c1 = fmaf(rB2, ww[6], c1);
    a0 = fmaf(rA3, wz[3], a0);
    a1 = fmaf(rA3, ww[3], a1);
    c0 = fmaf(rB3, wz[7], c0);
    c1 = fmaf(rB3, ww[7], c1);
    float fx = a0 + c0;
    float fy = a1 + c1;
    // 8-lane butterfly; every lane ends with the full 64-hidden sum.
    fx = dpp_add<0x141>(dpp_add<0x4E>(dpp_add<0xB1>(fx)));
    fy = dpp_add<0x141>(dpp_add<0x4E>(dpp_add<0xB1>(fy)));
    f0 = fx;
    f1 = fy;
  };

  // previous even-index state (for paired float4 stores)
  float y0 = y.x, y1 = y.y;
  float py0 = y0, py1 = y1;
  constexpr float DT = kDt, DT3 = kDt / 3.0f, DT8 = kDt / 8.0f;

  for (int s = 1; s <= kSteps; ++s) {
    float k1x, k1y, k2x, k2y, k3x, k3y, k4x, k4y;
    feval(y0, y1, k1x, k1y);
    feval(fmaf(DT3, k1x, y0), fmaf(DT3, k1y, y1), k2x, k2y);
    feval(fmaf(DT, k2x, fmaf(-DT3, k1x, y0)),
          fmaf(DT, k2y, fmaf(-DT3, k1y, y1)), k3x, k3y);
    feval(fmaf(DT, k1x - k2x + k3x, y0),
          fmaf(DT, k1y - k2y + k3y, y1), k4x, k4y);
    y0 = fmaf(DT8, k1x + 3.0f * (k2x + k3x) + k4x, y0);
    y1 = fmaf(DT8, k1y + 3.0f * (k2y + k3y) + k4y, y1);

    if (s & 1) {
      if (part == 0) {
        // write times (s-1, s) as one 16B store; offsets are 16B-aligned
        float4 v = make_float4(py0, py1, y0, y1);
        *reinterpret_cast<float4*>(op + (long)(s - 1) * 2) = v;
      }
    } else {
      py0 = y0;
      py1 = y1;
    }
  }
}

extern "C" void kernel_launch(void* const* d_in, const int* in_sizes, int n_in,
                              void* d_out, int out_size, void* d_ws,
                              size_t ws_size, hipStream_t stream) {
  const float* x = (const float*)d_in[0];
  const float* W1 = (const float*)d_in[1];
  const float* b1 = (const float*)d_in[2];
  const float* W2 = (const float*)d_in[3];
  const float* b2 = (const float*)d_in[4];
  float* out = (float*)d_out;

  dim3 grid(kB * kSplit / kBlock);  // 4096 blocks, 8 lanes per element
  dim3 block(kBlock);
  hipLaunchKernelGGL(ode_kernel, grid, block, 0, stream, x, W1, b1, W2, b2,
                     out);
}